// Round 2
// 69.542 us; speedup vs baseline: 1.1143x; 1.1143x over previous
//
#include <hip/hip_runtime.h>
#include <math.h>

// B=4096, IN_F=1024, NQ=4, L=2, C=256. One thread = one (b,c) 4-qubit circuit.
//
// R5: closed-form via Heisenberg (Pauli back-propagation), CORRECTED.
// Push each measured Z_q backward through ring-2 CNOTs (Z-parity masks),
// layer-1 RX (Z -> c Z + s Y), ring-1 CNOTs (Clifford, compile-time), then
// evaluate on the product state RX(a_q)|0>: <Z>=cos a, <Y>=-sin a, <X>=0.
//
// Ring-1 conjugated generators (conjugation order C30,C23,C12,C01):
//   Z0->Z1Z2Z3  Z1->Z0Z1  Z2->Z0Z1Z2  Z3->Z0Z1Z2Z3
//   Y0->X0Y1Z2Z3  Y1->Z0Y1X2  Y2->Z0Z1Y2X3  Y3->-Y0Y1Z2Y3
// Multiplying per-term (with Pauli phases) and dropping X-carrying strings
// leaves TEN terms (R4 wrongly had six):
//   a_q = x_q + w0_q ; C=cos a, S=sin a ; c=cos w1, s=sin w1
//   z0 = c1c2(c3 C0C1C3 + s3 S0S1S3) + s1s2(c3 C0S1S3 + s3 S0C1C3)
//   z1 = C3 (c0c1 C0C2 + s0s1 S0S2)
//   z2 = c0 (c1c2 C1C3 + s1s2 S1S3)
//   z3 = c1C0 (c0c2c3 C2 + s0s2s3 S2) + s1S0 (c0s2s3 C2 + s0c2c3 S2)
// Validated against hand-simulated full circuit in 6 configurations that
// exercise every term individually (incl. each term R4 missed), plus
// identity and basis-flip-chain checks. All match exactly.
//
// Per-thread: 16 native trig + ~35 VALU -> HBM-bound (33.5 MB traffic).

#define BQ 4096
#define CQ 256

__global__ __launch_bounds__(256) void qsim_kernel(
    const float* __restrict__ x,
    const float* __restrict__ w,
    float* __restrict__ out)
{
    const int tid = blockIdx.x * blockDim.x + threadIdx.x;   // [0, B*C)
    const int c = threadIdx.x;                               // blockDim == C == 256

    const float4 xv = reinterpret_cast<const float4*>(x)[tid];      // coalesced 16B
    const float4 w0 = reinterpret_cast<const float4*>(w)[c * 2 + 0]; // L1-resident 8KB
    const float4 w1 = reinterpret_cast<const float4*>(w)[c * 2 + 1];

    // Fused embedding + layer-0 full angles: RX(w0)RX(x) = RX(x+w0).
    const float a0 = xv.x + w0.x;
    const float a1 = xv.y + w0.y;
    const float a2 = xv.z + w0.z;
    const float a3 = xv.w + w0.w;

    const float C0 = __cosf(a0), S0 = __sinf(a0);
    const float C1 = __cosf(a1), S1 = __sinf(a1);
    const float C2 = __cosf(a2), S2 = __sinf(a2);
    const float C3 = __cosf(a3), S3 = __sinf(a3);

    // Layer-1 RX Heisenberg coefficients (full angles).
    const float c0 = __cosf(w1.x), s0 = __sinf(w1.x);
    const float c1 = __cosf(w1.y), s1 = __sinf(w1.y);
    const float c2 = __cosf(w1.z), s2 = __sinf(w1.z);
    const float c3 = __cosf(w1.w), s3 = __sinf(w1.w);

    // Shared subproducts.
    const float c1c2 = c1 * c2, s1s2 = s1 * s2;
    const float U = C1 * C3, V = S1 * S3;          // shared by z0, z2
    const float P = C0 * c3, Q = S0 * s3;          // z0

    // z0 = c1c2*(P*U + Q*V) + s1s2*(P*V + Q*U)
    const float z0 = fmaf(c1c2, fmaf(P, U, Q * V), s1s2 * fmaf(P, V, Q * U));
    // z1 = C3*(c0c1*C0C2 + s0s1*S0S2)
    const float z1 = C3 * fmaf(c0 * c1, C0 * C2, (s0 * s1) * (S0 * S2));
    // z2 = c0*(c1c2*U + s1s2*V)
    const float z2 = c0 * fmaf(c1c2, U, s1s2 * V);
    // z3 = c1C0*(E*G + F*H) + s1S0*(E*H + F*G),
    //   E = c0*C2, F = s0*S2, G = c2*c3, H = s2*s3
    const float E = c0 * C2, F = s0 * S2, G = c2 * c3, H = s2 * s3;
    const float z3 = fmaf(c1 * C0, fmaf(E, G, F * H), (s1 * S0) * fmaf(E, H, F * G));

    reinterpret_cast<float4*>(out)[tid] = make_float4(z0, z1, z2, z3);
}

extern "C" void kernel_launch(void* const* d_in, const int* in_sizes, int n_in,
                              void* d_out, int out_size, void* d_ws, size_t ws_size,
                              hipStream_t stream) {
    const float* x = (const float*)d_in[0];        // (4096, 1024) fp32
    const float* w = (const float*)d_in[1];        // (256, 2, 4) fp32
    float* out = (float*)d_out;                    // (4096, 1024) fp32

    const int total = BQ * CQ;                     // 1,048,576 threads
    qsim_kernel<<<total / 256, 256, 0, stream>>>(x, w, out);
}